// Round 5
// baseline (333.438 us; speedup 1.0000x reference)
//
#include <hip/hip_runtime.h>

#define NH 128
#define NW 128
#define ND 128
#define HWD (NH * NW * ND)
#define NB 2
#define NWND (NW * ND)

__device__ __forceinline__ float2 ld2(const float* p, int idx) {
    return *reinterpret_cast<const float2*>(p + idx);
}

__device__ __forceinline__ void polar_step(float U[3][3]) {
    float c00 = U[1][1]*U[2][2] - U[1][2]*U[2][1];
    float c01 = U[0][2]*U[2][1] - U[0][1]*U[2][2];
    float c02 = U[0][1]*U[1][2] - U[0][2]*U[1][1];
    float c10 = U[1][2]*U[2][0] - U[1][0]*U[2][2];
    float c11 = U[0][0]*U[2][2] - U[0][2]*U[2][0];
    float c12 = U[0][2]*U[1][0] - U[0][0]*U[1][2];
    float c20 = U[1][0]*U[2][1] - U[1][1]*U[2][0];
    float c21 = U[0][1]*U[2][0] - U[0][0]*U[2][1];
    float c22 = U[0][0]*U[1][1] - U[0][1]*U[1][0];
    float det = U[0][0]*c00 + U[0][1]*c10 + U[0][2]*c20;

    float l    = __log2f(fabsf(det));                               // v_log_f32
    float zeta = __builtin_amdgcn_exp2f(-0.33333333333333333f * l); // v_exp_f32
    float s    = copysignf(zeta * zeta, det);                       // 1/(zeta*det)
    float hz = 0.5f * zeta;
    float hs = 0.5f * s;

    float n00 = hz*U[0][0] + c00*hs;
    float n01 = hz*U[0][1] + c10*hs;
    float n02 = hz*U[0][2] + c20*hs;
    float n10 = hz*U[1][0] + c01*hs;
    float n11 = hz*U[1][1] + c11*hs;
    float n12 = hz*U[1][2] + c21*hs;
    float n20 = hz*U[2][0] + c02*hs;
    float n21 = hz*U[2][1] + c12*hs;
    float n22 = hz*U[2][2] + c22*hs;
    U[0][0]=n00; U[0][1]=n01; U[0][2]=n02;
    U[1][0]=n10; U[1][1]=n11; U[1][2]=n12;
    U[2][0]=n20; U[2][1]=n21; U[2][2]=n22;
}

__device__ __forceinline__ void gather6(const float* __restrict__ img,
                                        float cx, float cy, float cz,
                                        float acc[6]) {
    float flx = floorf(cx), fly = floorf(cy), flz = floorf(cz);
    float fx = cx - flx, fy = cy - fly, fz = cz - flz;
    int x0 = (int)flx, y0 = (int)fly, z0 = (int)flz;
    int xi[2], yi[2], zi[2];
    xi[0] = min(max(x0,     0), NH - 1); xi[1] = min(max(x0 + 1, 0), NH - 1);
    yi[0] = min(max(y0,     0), NW - 1); yi[1] = min(max(y0 + 1, 0), NW - 1);
    zi[0] = min(max(z0,     0), ND - 1); zi[1] = min(max(z0 + 1, 0), ND - 1);
    float wx[2] = {1.0f - fx, fx};
    float wy[2] = {1.0f - fy, fy};
    float wz[2] = {1.0f - fz, fz};
#pragma unroll
    for (int i = 0; i < 2; ++i) {
#pragma unroll
        for (int j = 0; j < 2; ++j) {
            int rowoff = (xi[i] * NW + yi[j]) * ND;
            float wij = wx[i] * wy[j];
#pragma unroll
            for (int k = 0; k < 2; ++k) {
                float wgt = wij * wz[k];
                int lin = rowoff + zi[k];
#pragma unroll
                for (int ch = 0; ch < 6; ++ch)
                    acc[ch] += wgt * img[ch * HWD + lin];
            }
        }
    }
}

__device__ __forceinline__ void transform(const float U[3][3], const float acc[6],
                                          float t[6]) {
    float Dm[3][3];
    Dm[0][0] = acc[0]; Dm[0][1] = acc[1]; Dm[0][2] = acc[3];
    Dm[1][0] = acc[1]; Dm[1][1] = acc[2]; Dm[1][2] = acc[4];
    Dm[2][0] = acc[3]; Dm[2][1] = acc[4]; Dm[2][2] = acc[5];
    float M[3][3];
#pragma unroll
    for (int i = 0; i < 3; ++i)
#pragma unroll
        for (int k = 0; k < 3; ++k)
            M[i][k] = U[0][i]*Dm[0][k] + U[1][i]*Dm[1][k] + U[2][i]*Dm[2][k];
    t[0] = M[0][0]*U[0][0] + M[0][1]*U[1][0] + M[0][2]*U[2][0];   // T00
    t[1] = M[1][0]*U[0][0] + M[1][1]*U[1][0] + M[1][2]*U[2][0];   // T10
    t[2] = M[1][0]*U[0][1] + M[1][1]*U[1][1] + M[1][2]*U[2][1];   // T11
    t[3] = M[2][0]*U[0][0] + M[2][1]*U[1][0] + M[2][2]*U[2][0];   // T20
    t[4] = M[2][0]*U[0][1] + M[2][1]*U[1][1] + M[2][2]*U[2][1];   // T21
    t[5] = M[2][0]*U[0][2] + M[2][1]*U[1][2] + M[2][2]*U[2][2];   // T22
}

__global__ __launch_bounds__(256) void warp_dti_kernel(
    const float* __restrict__ dti,
    const float* __restrict__ ddf,
    float* __restrict__ out)
{
    const int tid = blockIdx.x * 256 + threadIdx.x;   // grid == NB*HWD/2
    const int dz = tid & 63;                // z-pair index; lanes vary only here
    const int w  = (tid >> 6) & (NW - 1);   // wave-uniform
    const int h  = (tid >> 13) & (NH - 1);  // wave-uniform
    const int b  = tid >> 20;               // wave-uniform
    const int d0 = dz << 1;                 // even z
    const int sp0 = (h * NW + w) * ND + d0; // 8B-aligned pair base

    const float* dbase = ddf + b * 3 * HWD;

    // branchless edge handling: clamp index so the "missing" neighbor loads
    // the center (or adjacent) value, and scale 0.5 -> 1.0 at edges.
    const int hp_off = (h < NH - 1) ? sp0 + NWND : sp0;
    const int hm_off = (h > 0)      ? sp0 - NWND : sp0;
    const float shh  = (h > 0 && h < NH - 1) ? 0.5f : 1.0f;
    const int wp_off = (w < NW - 1) ? sp0 + ND : sp0;
    const int wm_off = (w > 0)      ? sp0 - ND : sp0;
    const float sww  = (w > 0 && w < NW - 1) ? 0.5f : 1.0f;
    const int zm_off = (dz > 0)  ? sp0 - 1 : sp0;      // -> u0 at z edge
    const int zp_off = (dz < 63) ? sp0 + 2 : sp0 + 1;  // -> u1 at z edge
    const float sd0  = (dz > 0)  ? 0.5f : 1.0f;
    const float sd1  = (dz < 63) ? 0.5f : 1.0f;

    float u0[3], u1[3];
    float A0[3][3], A1[3][3];
#pragma unroll
    for (int c = 0; c < 3; ++c) {
        const float* p = dbase + c * HWD;
        float2 u  = ld2(p, sp0);
        float2 hp = ld2(p, hp_off);
        float2 hm = ld2(p, hm_off);
        float2 wp = ld2(p, wp_off);
        float2 wm = ld2(p, wm_off);
        float  zm = p[zm_off];
        float  zp = p[zp_off];
        u0[c] = u.x; u1[c] = u.y;
        A0[c][0] = shh * (hp.x - hm.x);
        A1[c][0] = shh * (hp.y - hm.y);
        A0[c][1] = sww * (wp.x - wm.x);
        A1[c][1] = sww * (wp.y - wm.y);
        A0[c][2] = sd0 * (u.y - zm);
        A1[c][2] = sd1 * (zp - u.x);
    }
    A0[0][0] += 1.0f; A0[1][1] += 1.0f; A0[2][2] += 1.0f;
    A1[0][0] += 1.0f; A1[1][1] += 1.0f; A1[2][2] += 1.0f;

    // two independent Newton chains, interleaved per iteration for ILP
#pragma unroll
    for (int it = 0; it < 6; ++it) {
        polar_step(A0);
        polar_step(A1);
    }

    // two independent trilinear gathers
    const float* img = dti + b * 6 * HWD;
    float acc0[6] = {0,0,0,0,0,0};
    float acc1[6] = {0,0,0,0,0,0};
    gather6(img, (float)h + u0[0], (float)w + u0[1], (float)d0 + u0[2], acc0);
    gather6(img, (float)h + u1[0], (float)w + u1[1], (float)(d0 + 1) + u1[2], acc1);

    float t0[6], t1[6];
    transform(A0, acc0, t0);
    transform(A1, acc1, t1);

    float* obase = out + b * 6 * HWD + sp0;
#pragma unroll
    for (int ch = 0; ch < 6; ++ch)
        *reinterpret_cast<float2*>(obase + ch * HWD) = make_float2(t0[ch], t1[ch]);
}

extern "C" void kernel_launch(void* const* d_in, const int* in_sizes, int n_in,
                              void* d_out, int out_size, void* d_ws, size_t ws_size,
                              hipStream_t stream) {
    const float* dti = (const float*)d_in[0];
    const float* ddf = (const float*)d_in[1];
    float* o = (float*)d_out;
    const int n2 = NB * HWD / 2;   // 2,097,152 threads (z-pairs)
    warp_dti_kernel<<<n2 / 256, 256, 0, stream>>>(dti, ddf, o);
}